// Round 1
// baseline (148.846 us; speedup 1.0000x reference)
//
#include <hip/hip_runtime.h>
#include <math.h>

#define HW     16384
#define CDIM   10
#define NPIX   131072        // B*H*W
#define NPLANE 1310720       // B*C*H*W
#define BN_N   131072.0f
#define EPS_BN 1e-5f

__device__ __forceinline__ float sigf(float x) { return 1.0f / (1.0f + __expf(-x)); }
__device__ __forceinline__ float tanh_fast(float x) {
    x = fminf(fmaxf(x, -15.0f), 15.0f);
    float e = __expf(2.0f * x);
    return (e - 1.0f) / (e + 1.0f);
}

// DPP-based 64-lane sum: VALU-only, no LDS pipe. Result valid in lane 63.
template<int CTRL>
__device__ __forceinline__ float dpp_add(float x) {
    int t = __builtin_amdgcn_update_dpp(0, __float_as_int(x), CTRL, 0xF, 0xF, true);
    return x + __int_as_float(t);
}
__device__ __forceinline__ float wred63(float x) {
    x = dpp_add<0x111>(x);   // row_shr:1
    x = dpp_add<0x112>(x);   // row_shr:2
    x = dpp_add<0x114>(x);   // row_shr:4
    x = dpp_add<0x118>(x);   // row_shr:8  -> lane 15 of each row has row sum
    x = dpp_add<0x142>(x);   // row_bcast:15 -> lane 31 = sum(0..31), lane 63 = sum(32..63)
    x = dpp_add<0x143>(x);   // row_bcast:31 -> lane 63 = sum(0..63)
    return x;
}

// Kernel A: node0 (GRU0), comp_att, and BN1 stats of y1 = W_r1 @ [f1, (h1+h2)*att]
// Weights read from GLOBAL with uniform (compile-time) indices -> s_load / SGPR operands.
__global__ __launch_bounds__(256) void kernA(
    const float* __restrict__ f0, const float* __restrict__ f1,
    const float* __restrict__ h0, const float* __restrict__ h1, const float* __restrict__ h2,
    const float* __restrict__ W_att, const float* __restrict__ b_att,
    const float* __restrict__ W_r1,
    const float* __restrict__ Wg0, const float* __restrict__ bg0, const float* __restrict__ Wc0,
    float* __restrict__ node0, float* __restrict__ att_out, float* __restrict__ stats1)
{
    __shared__ float sPart[4 * 40];   // per-wave partials: [wave][40]
    const int tid = threadIdx.x;
    const int p = blockIdx.x * 256 + tid;
    const int b = p >> 14, s = p & 16383;
    const int base = b * (CDIM * HW) + s;
    const int wave = tid >> 6, lane = tid & 63;

    float vh1[10], vh2[10], vf1[10], vf0[10], vh0[10];
#pragma unroll
    for (int c = 0; c < 10; c++) {
        vh1[c] = h1[base + c * HW];
        vh2[c] = h2[base + c * HW];
        vf1[c] = f1[base + c * HW];
        vf0[c] = f0[base + c * HW];
        vh0[c] = h0[base + c * HW];
    }

    // node0 = GRU0(x=h0, h=f0)
    float g0 = bg0[0], g1 = bg0[1];
#pragma unroll
    for (int i = 0; i < 10; i++) {
        g0 = fmaf(Wg0[i],      vh0[i], fmaf(Wg0[10 + i], vf0[i], g0));
        g1 = fmaf(Wg0[20 + i], vh0[i], fmaf(Wg0[30 + i], vf0[i], g1));
    }
    const float r = sigf(g0), u = sigf(g1);
#pragma unroll
    for (int o = 0; o < 10; o++) {
        float acc = 0.0f;
#pragma unroll
        for (int i = 0; i < 10; i++) acc = fmaf(Wc0[o * 20 + i], vh0[i], acc);
#pragma unroll
        for (int i = 0; i < 10; i++) acc = fmaf(Wc0[o * 20 + 10 + i], r * vf0[i], acc);
        node0[base + o * HW] = (1.0f - u) * vf0[o] + u * tanh_fast(acc);
    }

    // comp_att
    float z = b_att[0];
#pragma unroll
    for (int c = 0; c < 10; c++) z = fmaf(W_att[c], vh1[c], fmaf(W_att[10 + c], vh2[c], z));
    const float att = sigf(z);
    att_out[p] = att;

    // x = [f1, (h1+h2)*att]; y1 = W_r1 @ x (stats only)
    float x[20];
#pragma unroll
    for (int c = 0; c < 10; c++) { x[c] = vf1[c]; x[10 + c] = (vh1[c] + vh2[c]) * att; }
#pragma unroll
    for (int o = 0; o < 20; o++) {
        float acc = 0.0f;
#pragma unroll
        for (int i = 0; i < 20; i++) acc = fmaf(W_r1[o * 20 + i], x[i], acc);
        float rs = wred63(acc);
        float rq = wred63(acc * acc);
        if (lane == 63) { sPart[wave * 40 + o] = rs; sPart[wave * 40 + 20 + o] = rq; }
    }
    __syncthreads();
    if (tid < 40) {
        float t = sPart[tid] + sPart[40 + tid] + sPart[80 + tid] + sPart[120 + tid];
        atomicAdd(&stats1[tid], t);
    }
}

// Kernel C: finalize BN1 (per-thread from uniform s_loads), recompute att + y1,
// BN1+ReLU, y2 = W_r2 @ x2, BN2 stats.
__global__ __launch_bounds__(256) void kernC(
    const float* __restrict__ f1, const float* __restrict__ h1, const float* __restrict__ h2,
    const float* __restrict__ W_att, const float* __restrict__ b_att,
    const float* __restrict__ W_r1, const float* __restrict__ g_r1, const float* __restrict__ be_r1,
    const float* __restrict__ W_r2,
    const float* __restrict__ stats1, float* __restrict__ y2out, float* __restrict__ stats2)
{
    __shared__ float sPart[4 * 20];
    const int tid = threadIdx.x;
    const int p = blockIdx.x * 256 + tid;
    const int b = p >> 14, s = p & 16383;
    const int base = b * (CDIM * HW) + s;
    const int wave = tid >> 6, lane = tid & 63;

    // BN1 coefficients — all inputs wave-uniform (s_load), small VALU per thread
    float A1[20], B1[20];
#pragma unroll
    for (int c = 0; c < 20; c++) {
        float mean = stats1[c] * (1.0f / BN_N);
        float var  = stats1[20 + c] * (1.0f / BN_N) - mean * mean;
        float a = g_r1[c] * rsqrtf(var + EPS_BN);
        A1[c] = a;
        B1[c] = be_r1[c] - mean * a;
    }

    float vh1[10], vh2[10], vf1[10];
#pragma unroll
    for (int c = 0; c < 10; c++) {
        vh1[c] = h1[base + c * HW];
        vh2[c] = h2[base + c * HW];
        vf1[c] = f1[base + c * HW];
    }
    // recompute att (cheaper than re-reading the att plane)
    float z = b_att[0];
#pragma unroll
    for (int c = 0; c < 10; c++) z = fmaf(W_att[c], vh1[c], fmaf(W_att[10 + c], vh2[c], z));
    const float att = sigf(z);

    float x[20];
#pragma unroll
    for (int c = 0; c < 10; c++) { x[c] = vf1[c]; x[10 + c] = (vh1[c] + vh2[c]) * att; }
    float x2[20];
#pragma unroll
    for (int o = 0; o < 20; o++) {
        float acc = 0.0f;
#pragma unroll
        for (int i = 0; i < 20; i++) acc = fmaf(W_r1[o * 20 + i], x[i], acc);
        x2[o] = fmaxf(fmaf(A1[o], acc, B1[o]), 0.0f);
    }
    const int base2 = b * (10 * HW) + s;
#pragma unroll
    for (int o = 0; o < 10; o++) {
        float acc = 0.0f;
#pragma unroll
        for (int i = 0; i < 20; i++) acc = fmaf(W_r2[o * 20 + i], x2[i], acc);
        y2out[base2 + o * HW] = acc;
        float rs = wred63(acc);
        float rq = wred63(acc * acc);
        if (lane == 63) { sPart[wave * 20 + o] = rs; sPart[wave * 20 + 10 + o] = rq; }
    }
    __syncthreads();
    if (tid < 20) {
        float t = sPart[tid] + sPart[20 + tid] + sPart[40 + tid] + sPart[60 + tid];
        atomicAdd(&stats2[tid], t);
    }
}

// Kernel E: finalize BN2 per-thread, comp_full = ReLU(BN2(y2)), node1 = GRU1(comp_full, f1)
__global__ __launch_bounds__(256) void kernE(
    const float* __restrict__ f1, const float* __restrict__ y2in,
    const float* __restrict__ stats2,
    const float* __restrict__ g_r2, const float* __restrict__ be_r2,
    const float* __restrict__ Wg1, const float* __restrict__ bg1, const float* __restrict__ Wc1,
    float* __restrict__ node1)
{
    const int tid = threadIdx.x;
    const int p = blockIdx.x * 256 + tid;
    const int b = p >> 14, s = p & 16383;
    const int base = b * (CDIM * HW) + s;

    float A2[10], B2[10];
#pragma unroll
    for (int c = 0; c < 10; c++) {
        float mean = stats2[c] * (1.0f / BN_N);
        float var  = stats2[10 + c] * (1.0f / BN_N) - mean * mean;
        float a = g_r2[c] * rsqrtf(var + EPS_BN);
        A2[c] = a;
        B2[c] = be_r2[c] - mean * a;
    }

    float comp[10], vf1[10];
#pragma unroll
    for (int c = 0; c < 10; c++) {
        vf1[c]  = f1[base + c * HW];
        comp[c] = fmaxf(fmaf(A2[c], y2in[base + c * HW], B2[c]), 0.0f);
    }
    float g0 = bg1[0], g1v = bg1[1];
#pragma unroll
    for (int i = 0; i < 10; i++) {
        g0  = fmaf(Wg1[i],      comp[i], fmaf(Wg1[10 + i], vf1[i], g0));
        g1v = fmaf(Wg1[20 + i], comp[i], fmaf(Wg1[30 + i], vf1[i], g1v));
    }
    const float r = sigf(g0), u = sigf(g1v);
#pragma unroll
    for (int o = 0; o < 10; o++) {
        float acc = 0.0f;
#pragma unroll
        for (int i = 0; i < 10; i++) acc = fmaf(Wc1[o * 20 + i], comp[i], acc);
#pragma unroll
        for (int i = 0; i < 10; i++) acc = fmaf(Wc1[o * 20 + 10 + i], r * vf1[i], acc);
        node1[base + o * HW] = (1.0f - u) * vf1[o] + u * tanh_fast(acc);
    }
}

extern "C" void kernel_launch(void* const* d_in, const int* in_sizes, int n_in,
                              void* d_out, int out_size, void* d_ws, size_t ws_size,
                              hipStream_t stream) {
    const float* f0    = (const float*)d_in[0];
    const float* f1    = (const float*)d_in[1];
    const float* h0    = (const float*)d_in[2];
    const float* h1    = (const float*)d_in[3];
    const float* h2    = (const float*)d_in[4];
    const float* W_att = (const float*)d_in[5];
    const float* b_att = (const float*)d_in[6];
    const float* W_r1  = (const float*)d_in[7];
    const float* g_r1  = (const float*)d_in[8];
    const float* be_r1 = (const float*)d_in[9];
    const float* W_r2  = (const float*)d_in[10];
    const float* g_r2  = (const float*)d_in[11];
    const float* be_r2 = (const float*)d_in[12];
    const float* Wg0   = (const float*)d_in[13];
    const float* bg0   = (const float*)d_in[14];
    const float* Wc0   = (const float*)d_in[15];
    const float* Wg1   = (const float*)d_in[16];
    const float* bg1   = (const float*)d_in[17];
    const float* Wc1   = (const float*)d_in[18];

    float* out   = (float*)d_out;
    float* node0 = out;
    float* node1 = out + NPLANE;
    float* attO  = out + 2 * NPLANE;

    float* y2     = (float*)d_ws;                 // NPIX*10 floats
    float* stats1 = y2 + (size_t)10 * NPIX;       // 40 floats
    float* stats2 = stats1 + 40;                  // 20 floats

    hipMemsetAsync(stats1, 0, 64 * sizeof(float), stream);

    dim3 grid(NPIX / 256), blk(256);
    kernA<<<grid, blk, 0, stream>>>(f0, f1, h0, h1, h2, W_att, b_att, W_r1,
                                    Wg0, bg0, Wc0, node0, attO, stats1);
    kernC<<<grid, blk, 0, stream>>>(f1, h1, h2, W_att, b_att, W_r1, g_r1, be_r1, W_r2,
                                    stats1, y2, stats2);
    kernE<<<grid, blk, 0, stream>>>(f1, y2, stats2, g_r2, be_r2, Wg1, bg1, Wc1,
                                    node1);
}